// Round 1
// baseline (454.585 us; speedup 1.0000x reference)
//
#include <hip/hip_runtime.h>
#include <math.h>

// Problem constants (fixed by the reference)
#define NNODES 4096
#define NFEAT_ 1024
#define NHID_  64
#define NHEADS_ 8
#define EMB_   512
#define MAXD   256          // max supported degree (mean ~41, max ~<80 at 1% density)
constexpr float ALPHA_ = 0.2f;

// ---------------------------------------------------------------------------
// Tiled fp32 GEMM:  C[M,N] = act( A[M,K] * op(B) + bias )
//   BT=false: op(B)=B with B stored [K,N] row-major   (used for x @ W[h])
//   BT=true : op(B)=B^T with B stored [N,K] row-major (PyTorch Linear W)
// ACT: 0 = none, 1 = relu
// Batched over blockIdx.z with element strides sB, sC (A shared).
// All of M,N multiples of 64; K multiple of 16 (true for every call site).
// ---------------------------------------------------------------------------
template<bool BT, int ACT>
__global__ __launch_bounds__(256) void gemm64(
    const float* __restrict__ A, const float* __restrict__ B,
    const float* __restrict__ bias, float* __restrict__ C,
    int M, int N, int K, long sB, long sC)
{
    constexpr int BM = 64, BN = 64, BK = 16;
    __shared__ float As[BK][BM + 1];
    __shared__ float Bs[BK][BN + 1];

    B += (long)blockIdx.z * sB;
    C += (long)blockIdx.z * sC;

    const int m0 = blockIdx.y * BM;
    const int n0 = blockIdx.x * BN;
    const int tid = threadIdx.x;
    const int tx = tid & 15;          // column group (4 cols)
    const int ty = tid >> 4;          // row group (4 rows)

    float acc[4][4] = {};

    for (int k0 = 0; k0 < K; k0 += BK) {
        // A tile 64x16: thread t -> row m = t>>2, k = (t&3)*4, float4 load
        {
            const int m = tid >> 2, k = (tid & 3) << 2;
            const float4 v = *(const float4*)(A + (long)(m0 + m) * K + k0 + k);
            As[k + 0][m] = v.x; As[k + 1][m] = v.y;
            As[k + 2][m] = v.z; As[k + 3][m] = v.w;
        }
        if (!BT) {
            // B[K,N]: thread t -> k = t>>4, n = (t&15)*4
            const int k = tid >> 4, n = (tid & 15) << 2;
            const float4 v = *(const float4*)(B + (long)(k0 + k) * N + n0 + n);
            Bs[k][n + 0] = v.x; Bs[k][n + 1] = v.y;
            Bs[k][n + 2] = v.z; Bs[k][n + 3] = v.w;
        } else {
            // B[N,K]: thread t -> n = t>>2, k = (t&3)*4
            const int n = tid >> 2, k = (tid & 3) << 2;
            const float4 v = *(const float4*)(B + (long)(n0 + n) * K + k0 + k);
            Bs[k + 0][n] = v.x; Bs[k + 1][n] = v.y;
            Bs[k + 2][n] = v.z; Bs[k + 3][n] = v.w;
        }
        __syncthreads();

        #pragma unroll
        for (int k = 0; k < BK; ++k) {
            float ra[4], rb[4];
            #pragma unroll
            for (int i = 0; i < 4; ++i) ra[i] = As[k][ty * 4 + i];
            #pragma unroll
            for (int j = 0; j < 4; ++j) rb[j] = Bs[k][tx * 4 + j];
            #pragma unroll
            for (int i = 0; i < 4; ++i)
                #pragma unroll
                for (int j = 0; j < 4; ++j)
                    acc[i][j] = fmaf(ra[i], rb[j], acc[i][j]);
        }
        __syncthreads();
    }

    #pragma unroll
    for (int i = 0; i < 4; ++i) {
        const int row = m0 + ty * 4 + i;
        const int col = n0 + tx * 4;
        float4 v;
        float* pv = &v.x;
        #pragma unroll
        for (int j = 0; j < 4; ++j) {
            float t = acc[i][j];
            if (bias) t += bias[col + j];
            if (ACT == 1) t = t > 0.f ? t : 0.f;
            pv[j] = t;
        }
        *(float4*)(C + (long)row * N + col) = v;
    }
}

// ---------------------------------------------------------------------------
// e_src[h,n] = Wh[h,n,:].a1[h]   e_dst[h,n] = Wh[h,n,:].a2[h]
// One wave (64 lanes == NHID) per (h,n).
// ---------------------------------------------------------------------------
__global__ __launch_bounds__(256) void attn_scores(
    const float* __restrict__ Wh, const float* __restrict__ a1,
    const float* __restrict__ a2, float* __restrict__ esrc,
    float* __restrict__ edst)
{
    const int wave = (blockIdx.x * 256 + threadIdx.x) >> 6;
    const int lane = threadIdx.x & 63;
    const int h = wave >> 12, n = wave & 4095;
    const float w = Wh[((long)h * NNODES + n) * NHID_ + lane];
    float s1 = w * a1[h * NHID_ + lane];
    float s2 = w * a2[h * NHID_ + lane];
    #pragma unroll
    for (int off = 32; off; off >>= 1) {
        s1 += __shfl_xor(s1, off);
        s2 += __shfl_xor(s2, off);
    }
    if (lane == 0) {
        esrc[h * NNODES + n] = s1;
        edst[h * NNODES + n] = s2;
    }
}

// ---------------------------------------------------------------------------
// Neighbor-list build from dense 0/1 adjacency. One block per row.
// Order within a list is arbitrary (softmax-weighted sum is order-robust).
// ---------------------------------------------------------------------------
__global__ __launch_bounds__(256) void build_nbr(
    const float* __restrict__ adj, int* __restrict__ cnt,
    int* __restrict__ nbr)
{
    __shared__ int lcnt;
    const int n = blockIdx.x;
    if (threadIdx.x == 0) lcnt = 0;
    __syncthreads();
    for (int m = threadIdx.x; m < NNODES; m += 256) {
        if (adj[(long)n * NNODES + m] != 0.f) {
            const int p = atomicAdd(&lcnt, 1);
            if (p < MAXD) nbr[n * MAXD + p] = m;
        }
    }
    __syncthreads();
    if (threadIdx.x == 0) cnt[n] = lcnt < MAXD ? lcnt : MAXD;
}

// ---------------------------------------------------------------------------
// Sparse masked softmax + weighted aggregation + ELU + transpose-to-enc.
// One wave per (h,n); 4 waves per block. Exact w.r.t. the dense reference:
// masked entries are exp(NEG - max) == 0 and never set the max (self-loop
// guarantees >=1 neighbor).
// ---------------------------------------------------------------------------
__global__ __launch_bounds__(256) void attn_agg(
    const float* __restrict__ Wh, const float* __restrict__ esrc,
    const float* __restrict__ edst, const int* __restrict__ cnt,
    const int* __restrict__ nbr, float* __restrict__ enc)
{
    __shared__ float pLds[4][MAXD];
    __shared__ int   mLds[4][MAXD];
    const int w = threadIdx.x >> 6, lane = threadIdx.x & 63;
    const int pair = blockIdx.x * 4 + w;
    const int h = pair >> 12, n = pair & 4095;

    const int deg = min(cnt[n], MAXD);
    const int* lst = nbr + n * MAXD;
    const float es = esrc[h * NNODES + n];

    float mymax = -3.4e38f;
    for (int j = lane; j < deg; j += 64) {
        const int m = lst[j];
        float ev = es + edst[h * NNODES + m];
        ev = ev > 0.f ? ev : ALPHA_ * ev;
        pLds[w][j] = ev;
        mLds[w][j] = m;
        mymax = fmaxf(mymax, ev);
    }
    #pragma unroll
    for (int off = 32; off; off >>= 1) mymax = fmaxf(mymax, __shfl_xor(mymax, off));

    float mysum = 0.f;
    for (int j = lane; j < deg; j += 64) {
        const float p = expf(pLds[w][j] - mymax);
        pLds[w][j] = p;
        mysum += p;
    }
    #pragma unroll
    for (int off = 32; off; off >>= 1) mysum += __shfl_xor(mysum, off);

    __syncthreads();   // cross-lane LDS visibility (each wave hits exactly once)

    // Phase 2: lane == output dim d. Coalesced 256B reads of Wh rows.
    float acc = 0.f;
    const float* WhH = Wh + (long)h * NNODES * NHID_;
    for (int j = 0; j < deg; ++j)
        acc = fmaf(pLds[w][j], WhH[(long)mLds[w][j] * NHID_ + lane], acc);

    float hv = acc / mysum;
    hv = hv > 0.f ? hv : expm1f(hv);                 // ELU
    enc[(long)n * EMB_ + h * NHID_ + lane] = hv;     // [N, H*nhid]
}

// ---------------------------------------------------------------------------
extern "C" void kernel_launch(void* const* d_in, const int* in_sizes, int n_in,
                              void* d_out, int out_size, void* d_ws, size_t ws_size,
                              hipStream_t stream)
{
    const float* x   = (const float*)d_in[0];
    const float* adj = (const float*)d_in[1];
    const float* W   = (const float*)d_in[2];
    const float* a1  = (const float*)d_in[3];
    const float* a2  = (const float*)d_in[4];
    const float* W1  = (const float*)d_in[5];
    const float* b1  = (const float*)d_in[6];
    const float* W2  = (const float*)d_in[7];
    const float* b2  = (const float*)d_in[8];
    const float* W3  = (const float*)d_in[9];
    const float* b3  = (const float*)d_in[10];
    const float* W4  = (const float*)d_in[11];
    const float* b4  = (const float*)d_in[12];
    float* out = (float*)d_out;

    // Workspace layout (floats). dd3 aliases Wh (Wh dead after attn_agg).
    float* Wh  = (float*)d_ws;                    // 8*4096*64 = 2,097,152
    float* es  = Wh  + 2097152;                   //    32,768
    float* ed  = es  + 32768;                     //    32,768
    float* enc = ed  + 32768;                     // 2,097,152
    float* dd1 = enc + 2097152;                   // 1,048,576
    float* dd2 = dd1 + 1048576;                   // 1,048,576
    int*   cnt = (int*)(dd2 + 1048576);           //     4,096
    int*   nbr = cnt + 4096;                      // 4096*256 = 1,048,576
    float* dd3 = Wh;                              // alias: 2,097,152 needed

    // 1) Wh[h] = x @ W[h]   (batched NN GEMM, 8 heads)
    gemm64<false, 0><<<dim3(1, 64, 8), 256, 0, stream>>>(
        x, W, nullptr, Wh, NNODES, NHID_, NFEAT_,
        (long)NFEAT_ * NHID_, (long)NNODES * NHID_);

    // 2) attention scores per node
    attn_scores<<<dim3(8192), 256, 0, stream>>>(Wh, a1, a2, es, ed);

    // 3) neighbor lists from dense adjacency
    build_nbr<<<dim3(NNODES), 256, 0, stream>>>(adj, cnt, nbr);

    // 4) sparse softmax + aggregate + ELU -> enc [N, 512]
    attn_agg<<<dim3(8192), 256, 0, stream>>>(Wh, es, ed, cnt, nbr, enc);

    // 5) decoder MLP (PyTorch Linear: y = x @ W^T + b)
    gemm64<true, 1><<<dim3(4,  64, 1), 256, 0, stream>>>(enc, W1, b1, dd1, NNODES, 256, 512, 0, 0);
    gemm64<true, 1><<<dim3(4,  64, 1), 256, 0, stream>>>(dd1, W2, b2, dd2, NNODES, 256, 256, 0, 0);
    gemm64<true, 1><<<dim3(8,  64, 1), 256, 0, stream>>>(dd2, W3, b3, dd3, NNODES, 512, 256, 0, 0);
    gemm64<true, 0><<<dim3(16, 64, 1), 256, 0, stream>>>(dd3, W4, b4, out, NNODES, 1024, 512, 0, 0);
}

// Round 2
// 271.340 us; speedup vs baseline: 1.6753x; 1.6753x over previous
//
#include <hip/hip_runtime.h>
#include <hip/hip_bf16.h>
#include <math.h>

// Problem constants (fixed by the reference)
#define NNODES 4096
#define NFEAT_ 1024
#define NHID_  64
#define NHEADS_ 8
#define EMB_   512
#define MAXD   256
constexpr float ALPHA_ = 0.2f;

typedef __attribute__((ext_vector_type(8))) short bf16x8;  // 8 bf16 (4 VGPRs)
typedef __attribute__((ext_vector_type(4))) float f32x4;   // MFMA accumulator

__device__ inline unsigned short f2b(float f) {
    __hip_bfloat16 b = __float2bfloat16(f);
    return *(unsigned short*)&b;
}

// ---------------------------------------------------------------------------
// bf16 MFMA GEMM:  C[M,N] = act( A[M,K] @ B[N,K]^T + bias )
// A, B bf16 row-major (B in "B^T" form: row n holds the K-vector of out col n).
// 256 threads = 4 waves in 2x2; BM=128, BK=32; wave tile 64 x (BN/2).
// OUTBF: write bf16, else fp32.  ACT: 1 = relu.
// M % 128 == 0, N % BN == 0, K % 32 == 0 at every call site.
// ---------------------------------------------------------------------------
template<int BN, bool OUTBF, int ACT>
__global__ __launch_bounds__(256) void gemm_bt(
    const unsigned short* __restrict__ A, const unsigned short* __restrict__ B,
    const float* __restrict__ bias, void* __restrict__ Cv,
    int M, int N, int K)
{
    constexpr int BM = 128, BK = 32;
    constexpr int NJ = BN / 32;       // B fragments per wave
    constexpr int WN = BN / 2;        // wave column extent
    __shared__ __align__(16) unsigned short As[BM * BK];
    __shared__ __align__(16) unsigned short Bs[BN * BK];

    const int tid  = threadIdx.x;
    const int wid  = tid >> 6, lane = tid & 63;
    const int wr   = wid >> 1, wc = wid & 1;
    const int m0   = blockIdx.y * BM, n0 = blockIdx.x * BN;
    const int frow = lane & 15, fk = (lane >> 4) * 8;

    f32x4 acc[4][NJ] = {};

    for (int k0 = 0; k0 < K; k0 += BK) {
        // stage A tile [128][32] bf16 (8 KB): 512 chunks of 16 B, linear in LDS
        const uint4* ga = (const uint4*)(A + (long)m0 * K + k0);
        #pragma unroll
        for (int i = 0; i < 2; ++i) {
            const int c = i * 256 + tid;
            ((uint4*)As)[c] = ga[(long)(c >> 2) * (K >> 3) + (c & 3)];
        }
        // stage B tile [BN][32]
        const uint4* gb = (const uint4*)(B + (long)n0 * K + k0);
        #pragma unroll
        for (int i = 0; i < BN / 64; ++i) {
            const int c = i * 256 + tid;
            ((uint4*)Bs)[c] = gb[(long)(c >> 2) * (K >> 3) + (c & 3)];
        }
        __syncthreads();

        bf16x8 af[4], bfr[NJ];
        #pragma unroll
        for (int i = 0; i < 4; ++i)
            af[i] = *(const bf16x8*)&As[(wr * 64 + i * 16 + frow) * BK + fk];
        #pragma unroll
        for (int j = 0; j < NJ; ++j)
            bfr[j] = *(const bf16x8*)&Bs[(wc * WN + j * 16 + frow) * BK + fk];
        #pragma unroll
        for (int i = 0; i < 4; ++i)
            #pragma unroll
            for (int j = 0; j < NJ; ++j)
                acc[i][j] = __builtin_amdgcn_mfma_f32_16x16x32_bf16(
                    af[i], bfr[j], acc[i][j], 0, 0, 0);
        __syncthreads();
    }

    // epilogue: C/D layout col=lane&15, row=(lane>>4)*4+reg  [m89-verified]
    const int crow0 = m0 + wr * 64 + (lane >> 4) * 4;
    const int ccol0 = n0 + wc * WN + (lane & 15);
    #pragma unroll
    for (int i = 0; i < 4; ++i)
        #pragma unroll
        for (int j = 0; j < NJ; ++j)
            #pragma unroll
            for (int r = 0; r < 4; ++r) {
                const int row = crow0 + i * 16 + r;
                const int col = ccol0 + j * 16;
                float v = acc[i][j][r];
                if (bias) v += bias[col];
                if (ACT == 1) v = v > 0.f ? v : 0.f;
                if (OUTBF) ((unsigned short*)Cv)[(long)row * N + col] = f2b(v);
                else       ((float*)Cv)[(long)row * N + col] = v;
            }
}

// ---------------------------------------------------------------------------
// Prep: cast x -> bf16; build WcatT[h*64+d][k] = W[h][k][d] (bf16, B^T form
// so head GEMM output lands directly in enc layout [n, h*64+d]);
// cast decoder weights to bf16.
// ---------------------------------------------------------------------------
__global__ __launch_bounds__(256) void prep(
    const float* __restrict__ x,  const float* __restrict__ W,
    const float* __restrict__ W1, const float* __restrict__ W2,
    const float* __restrict__ W3, const float* __restrict__ W4,
    unsigned short* __restrict__ xb,  unsigned short* __restrict__ WcT,
    unsigned short* __restrict__ W1b, unsigned short* __restrict__ W2b,
    unsigned short* __restrict__ W3b, unsigned short* __restrict__ W4b)
{
    const int np = gridDim.x * 256;
    const int t  = blockIdx.x * 256 + threadIdx.x;

    // x: 4096x1024 as float4
    for (int i = t; i < (NNODES * NFEAT_) / 4; i += np) {
        const float4 v = ((const float4*)x)[i];
        ushort4 o; o.x = f2b(v.x); o.y = f2b(v.y); o.z = f2b(v.z); o.w = f2b(v.w);
        ((ushort4*)xb)[i] = o;
    }
    // WcatT: [512][1024]
    for (int i = t; i < EMB_ * NFEAT_; i += np) {
        const int nrow = i >> 10, k = i & 1023;
        const int h = nrow >> 6, d = nrow & 63;
        WcT[i] = f2b(W[((long)h * NFEAT_ + k) * NHID_ + d]);
    }
    // decoder weights, plain cast via float4
    for (int i = t; i < (256 * 512) / 4; i += np) {
        const float4 v = ((const float4*)W1)[i];
        ushort4 o; o.x = f2b(v.x); o.y = f2b(v.y); o.z = f2b(v.z); o.w = f2b(v.w);
        ((ushort4*)W1b)[i] = o;
    }
    for (int i = t; i < (256 * 256) / 4; i += np) {
        const float4 v = ((const float4*)W2)[i];
        ushort4 o; o.x = f2b(v.x); o.y = f2b(v.y); o.z = f2b(v.z); o.w = f2b(v.w);
        ((ushort4*)W2b)[i] = o;
    }
    for (int i = t; i < (512 * 256) / 4; i += np) {
        const float4 v = ((const float4*)W3)[i];
        ushort4 o; o.x = f2b(v.x); o.y = f2b(v.y); o.z = f2b(v.z); o.w = f2b(v.w);
        ((ushort4*)W3b)[i] = o;
    }
    for (int i = t; i < (1024 * 512) / 4; i += np) {
        const float4 v = ((const float4*)W4)[i];
        ushort4 o; o.x = f2b(v.x); o.y = f2b(v.y); o.z = f2b(v.z); o.w = f2b(v.w);
        ((ushort4*)W4b)[i] = o;
    }
}

// ---------------------------------------------------------------------------
// e_src[h,n] = Whc[n, h*64+:].a1[h]   e_dst likewise. One wave per (h,n).
// Whc layout: [N, H*nhid] fp32.
// ---------------------------------------------------------------------------
__global__ __launch_bounds__(256) void attn_scores(
    const float* __restrict__ Whc, const float* __restrict__ a1,
    const float* __restrict__ a2, float* __restrict__ esrc,
    float* __restrict__ edst)
{
    const int wave = (blockIdx.x * 256 + threadIdx.x) >> 6;
    const int lane = threadIdx.x & 63;
    const int h = wave >> 12, n = wave & 4095;
    const float w = Whc[(long)n * EMB_ + h * NHID_ + lane];
    float s1 = w * a1[h * NHID_ + lane];
    float s2 = w * a2[h * NHID_ + lane];
    #pragma unroll
    for (int off = 32; off; off >>= 1) {
        s1 += __shfl_xor(s1, off);
        s2 += __shfl_xor(s2, off);
    }
    if (lane == 0) {
        esrc[h * NNODES + n] = s1;
        edst[h * NNODES + n] = s2;
    }
}

// ---------------------------------------------------------------------------
// Neighbor-list build from dense 0/1 adjacency. One block per row.
// ---------------------------------------------------------------------------
__global__ __launch_bounds__(256) void build_nbr(
    const float* __restrict__ adj, int* __restrict__ cnt,
    int* __restrict__ nbr)
{
    __shared__ int lcnt;
    const int n = blockIdx.x;
    if (threadIdx.x == 0) lcnt = 0;
    __syncthreads();
    for (int m = threadIdx.x; m < NNODES; m += 256) {
        if (adj[(long)n * NNODES + m] != 0.f) {
            const int p = atomicAdd(&lcnt, 1);
            if (p < MAXD) nbr[n * MAXD + p] = m;
        }
    }
    __syncthreads();
    if (threadIdx.x == 0) cnt[n] = lcnt < MAXD ? lcnt : MAXD;
}

// ---------------------------------------------------------------------------
// Sparse masked softmax + aggregation + ELU -> enc (bf16, [N, H*nhid]).
// One wave per (h,n). Exact vs dense reference (self-loop => deg >= 1).
// ---------------------------------------------------------------------------
__global__ __launch_bounds__(256) void attn_agg(
    const float* __restrict__ Whc, const float* __restrict__ esrc,
    const float* __restrict__ edst, const int* __restrict__ cnt,
    const int* __restrict__ nbr, unsigned short* __restrict__ enc)
{
    __shared__ float pLds[4][MAXD];
    __shared__ int   mLds[4][MAXD];
    const int w = threadIdx.x >> 6, lane = threadIdx.x & 63;
    const int pair = blockIdx.x * 4 + w;
    const int h = pair >> 12, n = pair & 4095;

    const int deg = min(cnt[n], MAXD);
    const int* lst = nbr + n * MAXD;
    const float es = esrc[h * NNODES + n];

    float mymax = -3.4e38f;
    for (int j = lane; j < deg; j += 64) {
        const int m = lst[j];
        float ev = es + edst[h * NNODES + m];
        ev = ev > 0.f ? ev : ALPHA_ * ev;
        pLds[w][j] = ev;
        mLds[w][j] = m;
        mymax = fmaxf(mymax, ev);
    }
    #pragma unroll
    for (int off = 32; off; off >>= 1) mymax = fmaxf(mymax, __shfl_xor(mymax, off));

    float mysum = 0.f;
    for (int j = lane; j < deg; j += 64) {
        const float p = expf(pLds[w][j] - mymax);
        pLds[w][j] = p;
        mysum += p;
    }
    #pragma unroll
    for (int off = 32; off; off >>= 1) mysum += __shfl_xor(mysum, off);

    __syncthreads();

    // Phase 2: lane == output dim d; 256 B coalesced reads of Whc rows.
    float acc = 0.f;
    for (int j = 0; j < deg; ++j)
        acc = fmaf(pLds[w][j], Whc[(long)mLds[w][j] * EMB_ + h * NHID_ + lane], acc);

    float hv = acc / mysum;
    hv = hv > 0.f ? hv : expm1f(hv);                       // ELU
    enc[(long)n * EMB_ + h * NHID_ + lane] = f2b(hv);
}

// ---------------------------------------------------------------------------
extern "C" void kernel_launch(void* const* d_in, const int* in_sizes, int n_in,
                              void* d_out, int out_size, void* d_ws, size_t ws_size,
                              hipStream_t stream)
{
    const float* x   = (const float*)d_in[0];
    const float* adj = (const float*)d_in[1];
    const float* W   = (const float*)d_in[2];
    const float* a1  = (const float*)d_in[3];
    const float* a2  = (const float*)d_in[4];
    const float* W1  = (const float*)d_in[5];
    const float* b1  = (const float*)d_in[6];
    const float* W2  = (const float*)d_in[7];
    const float* b2  = (const float*)d_in[8];
    const float* W3  = (const float*)d_in[9];
    const float* b3  = (const float*)d_in[10];
    const float* W4  = (const float*)d_in[11];
    const float* b4  = (const float*)d_in[12];
    float* out = (float*)d_out;

    // Workspace layout. xb dead after head GEMM -> aliased by dd1/dd2/dd3.
    float* Whc = (float*)d_ws;                       // 2,097,152 f  (8 MB)
    float* es  = Whc + 2097152;                      //    32,768 f
    float* ed  = es  + 32768;                        //    32,768 f
    unsigned short* enc = (unsigned short*)(ed + 32768);   // 2,097,152 bf16
    unsigned short* WcT = enc + 2097152;             //   524,288 bf16
    unsigned short* W1b = WcT + 524288;              //   131,072 bf16
    unsigned short* W2b = W1b + 131072;              //    65,536 bf16
    unsigned short* W3b = W2b + 65536;               //   131,072 bf16
    unsigned short* W4b = W3b + 131072;              //   524,288 bf16
    int* cnt = (int*)(W4b + 524288);                 //     4,096 i
    int* nbr = cnt + 4096;                           // 1,048,576 i
    unsigned short* xb  = (unsigned short*)(nbr + 1048576); // 4,194,304 bf16
    unsigned short* dd1 = xb;                        // 1,048,576 bf16 (alias)
    unsigned short* dd2 = dd1 + 1048576;             // 1,048,576 bf16
    unsigned short* dd3 = dd2 + 1048576;             // 2,097,152 bf16

    // 0) casts + weight transpose
    prep<<<dim3(256), 256, 0, stream>>>(x, W, W1, W2, W3, W4,
                                        xb, WcT, W1b, W2b, W3b, W4b);

    // 1) head GEMM: Whc[n, h*64+d] = x @ Wcat   (fp32 out for exact attention)
    gemm_bt<64, false, 0><<<dim3(8, 32), 256, 0, stream>>>(
        xb, WcT, nullptr, Whc, NNODES, EMB_, NFEAT_);

    // 2) attention scores
    attn_scores<<<dim3(8192), 256, 0, stream>>>(Whc, a1, a2, es, ed);

    // 3) neighbor lists
    build_nbr<<<dim3(NNODES), 256, 0, stream>>>(adj, cnt, nbr);

    // 4) sparse softmax + aggregate + ELU -> enc (bf16)
    attn_agg<<<dim3(8192), 256, 0, stream>>>(Whc, es, ed, cnt, nbr, enc);

    // 5) decoder MLP (y = x @ W^T + b), bf16 MFMA, fp32 accum
    gemm_bt<64, true, 1><<<dim3(4, 32), 256, 0, stream>>>(enc, W1b, b1, dd1, NNODES, 256, 512);
    gemm_bt<64, true, 1><<<dim3(4, 32), 256, 0, stream>>>(dd1, W2b, b2, dd2, NNODES, 256, 256);
    gemm_bt<64, true, 1><<<dim3(8, 32), 256, 0, stream>>>(dd2, W3b, b3, dd3, NNODES, 512, 256);
    gemm_bt<128, false, 0><<<dim3(8, 32), 256, 0, stream>>>(dd3, W4b, b4, out, NNODES, 1024, 512);
}

// Round 4
// 266.757 us; speedup vs baseline: 1.7041x; 1.0172x over previous
//
#include <hip/hip_runtime.h>
#include <hip/hip_bf16.h>
#include <math.h>

// Problem constants (fixed by the reference)
#define NNODES 4096
#define NFEAT_ 1024
#define NHID_  64
#define NHEADS_ 8
#define EMB_   512
#define MAXD   256
constexpr float ALPHA_ = 0.2f;

typedef __attribute__((ext_vector_type(8))) short bf16x8;  // 8 bf16 (4 VGPRs)
typedef __attribute__((ext_vector_type(4))) float f32x4;   // MFMA accumulator
typedef unsigned int u32;
typedef unsigned short u16;

__device__ inline u16 f2b(float f) {
    __hip_bfloat16 b = __float2bfloat16(f);
    return *(u16*)&b;
}
__device__ inline float b2f(u16 u) {
    return __uint_as_float(((u32)u) << 16);
}

// async global->LDS, 16 B per lane. LDS dest: wave-uniform base + lane*16.
__device__ inline void cp16(const void* g, void* l) {
    __builtin_amdgcn_global_load_lds(
        (const __attribute__((address_space(1))) u32*)g,
        (__attribute__((address_space(3))) u32*)l, 16, 0, 0);
}

// ---------------------------------------------------------------------------
// bf16 MFMA GEMM:  C[M,N] = act( A[M,K] @ B[N,K]^T + bias )
// A, B bf16 row-major (B in B^T form). BM=128, BK=32, 4 waves (2x2).
// Staging via global_load_lds (16 B), linear LDS layout (m97 structure).
// OUTM: 0 = fp32 out, 1 = bf16 out, 2 = fp32 out + bf16 mirror (Cb).
// ACT: 1 = relu.  M%128==0, N%BN==0, K%32==0 at every call site.
// ---------------------------------------------------------------------------
template<int BN, int OUTM, int ACT>
__global__ __launch_bounds__(256) void gemm_bt(
    const u16* __restrict__ A, const u16* __restrict__ B,
    const float* __restrict__ bias, void* __restrict__ Cv,
    u16* __restrict__ Cb, int M, int N, int K)
{
    constexpr int BM = 128, BK = 32;
    constexpr int WN = BN / 2;        // wave column extent
    constexpr int NJ = WN / 16;       // B fragments per wave
    constexpr int BCH = BN / 16;      // B 1KB chunks per K-tile (A has 8)
    __shared__ __align__(16) u16 As[BM * BK];
    __shared__ __align__(16) u16 Bs[BN * BK];

    const int tid  = threadIdx.x;
    const int wid  = tid >> 6, lane = tid & 63;
    const int wr   = wid >> 1, wc = wid & 1;
    const int m0   = blockIdx.y * BM, n0 = blockIdx.x * BN;
    const int frow = lane & 15, fk = (lane >> 4) * 8;
    const int lr   = lane >> 2, lc = (lane & 3) * 8;   // within-chunk row/col

    f32x4 acc[4][NJ] = {};

    for (int k0 = 0; k0 < K; k0 += BK) {
        // A tile [128][32] bf16 = 8 chunks of 1KB; wave w issues chunks w, w+4
        {
            const u16* gA = A + (long)m0 * K + k0;
            int c = wid;
            cp16(gA + (long)(c * 16 + lr) * K + lc, &As[c * 512]);
            c = wid + 4;
            cp16(gA + (long)(c * 16 + lr) * K + lc, &As[c * 512]);
        }
        // B tile [BN][32] = BCH chunks
        {
            const u16* gB = B + (long)n0 * K + k0;
            if (BCH >= 4) {
                int c = wid;
                cp16(gB + (long)(c * 16 + lr) * K + lc, &Bs[c * 512]);
                if (BCH == 8) {
                    c = wid + 4;
                    cp16(gB + (long)(c * 16 + lr) * K + lc, &Bs[c * 512]);
                }
            } else if (wid < BCH) {
                const int c = wid;
                cp16(gB + (long)(c * 16 + lr) * K + lc, &Bs[c * 512]);
            }
        }
        __syncthreads();   // compiler drains vmcnt(0) before s_barrier

        bf16x8 af[4], bfr[NJ];
        #pragma unroll
        for (int i = 0; i < 4; ++i)
            af[i] = *(const bf16x8*)&As[(wr * 64 + i * 16 + frow) * BK + fk];
        #pragma unroll
        for (int j = 0; j < NJ; ++j)
            bfr[j] = *(const bf16x8*)&Bs[(wc * WN + j * 16 + frow) * BK + fk];
        #pragma unroll
        for (int i = 0; i < 4; ++i)
            #pragma unroll
            for (int j = 0; j < NJ; ++j)
                acc[i][j] = __builtin_amdgcn_mfma_f32_16x16x32_bf16(
                    af[i], bfr[j], acc[i][j], 0, 0, 0);
        __syncthreads();
    }

    // epilogue: C/D layout col=lane&15, row=(lane>>4)*4+reg  [m89-verified]
    const int crow0 = m0 + wr * 64 + (lane >> 4) * 4;
    const int ccol0 = n0 + wc * WN + (lane & 15);
    #pragma unroll
    for (int i = 0; i < 4; ++i)
        #pragma unroll
        for (int j = 0; j < NJ; ++j)
            #pragma unroll
            for (int r = 0; r < 4; ++r) {
                const int row = crow0 + i * 16 + r;
                const int col = ccol0 + j * 16;
                float v = acc[i][j][r];
                if (bias) v += bias[col];
                if (ACT == 1) v = v > 0.f ? v : 0.f;
                if (OUTM == 1) ((u16*)Cv)[(long)row * N + col] = f2b(v);
                else           ((float*)Cv)[(long)row * N + col] = v;
                if (OUTM == 2) Cb[(long)row * N + col] = f2b(v);
            }
}

// ---------------------------------------------------------------------------
// Fused prep + neighbor-list build.
//   blocks [0, 4096)      : build_nbr row b from dense adjacency (float4 scan)
//   blocks [4096, 4224)   : WcT LDS tile-transpose (8 heads x 16 k-tiles)
//   blocks [4224, 4480)   : bf16 casts of x and decoder weights (grid-stride)
// ---------------------------------------------------------------------------
__global__ __launch_bounds__(256) void prep_nbr(
    const float* __restrict__ x,   const float* __restrict__ adj,
    const float* __restrict__ W,
    const float* __restrict__ W1,  const float* __restrict__ W2,
    const float* __restrict__ W3,  const float* __restrict__ W4,
    u16* __restrict__ xb,  u16* __restrict__ WcT,
    u16* __restrict__ W1b, u16* __restrict__ W2b,
    u16* __restrict__ W3b, u16* __restrict__ W4b,
    int* __restrict__ cnt, int* __restrict__ nbr)
{
    const int b = blockIdx.x, tid = threadIdx.x;

    if (b < NNODES) {
        // ---- neighbor list for row b ----
        __shared__ int lcnt;
        if (tid == 0) lcnt = 0;
        __syncthreads();
        const float4* arow = (const float4*)(adj + (long)b * NNODES);
        for (int m4 = tid; m4 < NNODES / 4; m4 += 256) {
            const float4 v = arow[m4];
            if (v.x != 0.f) { const int p = atomicAdd(&lcnt, 1); if (p < MAXD) nbr[b * MAXD + p] = m4 * 4; }
            if (v.y != 0.f) { const int p = atomicAdd(&lcnt, 1); if (p < MAXD) nbr[b * MAXD + p] = m4 * 4 + 1; }
            if (v.z != 0.f) { const int p = atomicAdd(&lcnt, 1); if (p < MAXD) nbr[b * MAXD + p] = m4 * 4 + 2; }
            if (v.w != 0.f) { const int p = atomicAdd(&lcnt, 1); if (p < MAXD) nbr[b * MAXD + p] = m4 * 4 + 3; }
        }
        __syncthreads();
        if (tid == 0) cnt[b] = lcnt < MAXD ? lcnt : MAXD;
    } else if (b < NNODES + 128) {
        // ---- WcT[h*64+d][k] = W[h][k][d], 64x64 tile via LDS ----
        __shared__ float tile[64][65];
        const int tb = b - NNODES;
        const int h = tb >> 4, k0 = (tb & 15) * 64;
        #pragma unroll
        for (int p = 0; p < 4; ++p) {
            const int kr = p * 16 + (tid >> 4), d = (tid & 15) * 4;
            const float4 v = *(const float4*)&W[((long)h * NFEAT_ + k0 + kr) * NHID_ + d];
            tile[kr][d] = v.x; tile[kr][d + 1] = v.y;
            tile[kr][d + 2] = v.z; tile[kr][d + 3] = v.w;
        }
        __syncthreads();
        #pragma unroll
        for (int p = 0; p < 4; ++p) {
            const int d = p * 16 + (tid >> 4), k = (tid & 15) * 4;
            ushort4 o;
            o.x = f2b(tile[k][d]);     o.y = f2b(tile[k + 1][d]);
            o.z = f2b(tile[k + 2][d]); o.w = f2b(tile[k + 3][d]);
            *(ushort4*)&WcT[((long)h * 64 + d) * NFEAT_ + k0 + k] = o;
        }
    } else {
        // ---- bf16 casts, grid-stride over 256 blocks ----
        const int np = 256 * 256;
        const int t = (b - NNODES - 128) * 256 + tid;
        for (int i = t; i < (NNODES * NFEAT_) / 4; i += np) {
            const float4 v = ((const float4*)x)[i];
            ushort4 o; o.x = f2b(v.x); o.y = f2b(v.y); o.z = f2b(v.z); o.w = f2b(v.w);
            ((ushort4*)xb)[i] = o;
        }
        for (int i = t; i < (256 * 512) / 4; i += np) {
            const float4 v = ((const float4*)W1)[i];
            ushort4 o; o.x = f2b(v.x); o.y = f2b(v.y); o.z = f2b(v.z); o.w = f2b(v.w);
            ((ushort4*)W1b)[i] = o;
        }
        for (int i = t; i < (256 * 256) / 4; i += np) {
            const float4 v = ((const float4*)W2)[i];
            ushort4 o; o.x = f2b(v.x); o.y = f2b(v.y); o.z = f2b(v.z); o.w = f2b(v.w);
            ((ushort4*)W2b)[i] = o;
        }
        for (int i = t; i < (512 * 256) / 4; i += np) {
            const float4 v = ((const float4*)W3)[i];
            ushort4 o; o.x = f2b(v.x); o.y = f2b(v.y); o.z = f2b(v.z); o.w = f2b(v.w);
            ((ushort4*)W3b)[i] = o;
        }
        for (int i = t; i < (1024 * 512) / 4; i += np) {
            const float4 v = ((const float4*)W4)[i];
            ushort4 o; o.x = f2b(v.x); o.y = f2b(v.y); o.z = f2b(v.z); o.w = f2b(v.w);
            ((ushort4*)W4b)[i] = o;
        }
    }
}

// ---------------------------------------------------------------------------
// e_src[h,n] = Whc[n, h*64+:].a1[h]   e_dst likewise. One wave per (h,n).
// Whc layout: [N, H*nhid] fp32 (exact scores).
// ---------------------------------------------------------------------------
__global__ __launch_bounds__(256) void attn_scores(
    const float* __restrict__ Whc, const float* __restrict__ a1,
    const float* __restrict__ a2, float* __restrict__ esrc,
    float* __restrict__ edst)
{
    const int wave = (blockIdx.x * 256 + threadIdx.x) >> 6;
    const int lane = threadIdx.x & 63;
    const int h = wave >> 12, n = wave & 4095;
    const float w = Whc[(long)n * EMB_ + h * NHID_ + lane];
    float s1 = w * a1[h * NHID_ + lane];
    float s2 = w * a2[h * NHID_ + lane];
    #pragma unroll
    for (int off = 32; off; off >>= 1) {
        s1 += __shfl_xor(s1, off);
        s2 += __shfl_xor(s2, off);
    }
    if (lane == 0) {
        esrc[h * NNODES + n] = s1;
        edst[h * NNODES + n] = s2;
    }
}

// ---------------------------------------------------------------------------
// Sparse masked softmax + aggregation + ELU -> enc (bf16, [N, H*nhid]).
// One wave per (h,n). Softmax in fp32 (exact); aggregation source is the
// bf16 mirror Whb (halves L2 traffic vs fp32 rows).
// ---------------------------------------------------------------------------
__global__ __launch_bounds__(256) void attn_agg(
    const u16* __restrict__ Whb, const float* __restrict__ esrc,
    const float* __restrict__ edst, const int* __restrict__ cnt,
    const int* __restrict__ nbr, u16* __restrict__ enc)
{
    __shared__ float pLds[4][MAXD];
    __shared__ int   mLds[4][MAXD];
    const int w = threadIdx.x >> 6, lane = threadIdx.x & 63;
    const int pair = blockIdx.x * 4 + w;
    const int h = pair >> 12, n = pair & 4095;

    const int deg = min(cnt[n], MAXD);
    const int* lst = nbr + n * MAXD;
    const float es = esrc[h * NNODES + n];

    float mymax = -3.4e38f;
    for (int j = lane; j < deg; j += 64) {
        const int m = lst[j];
        float ev = es + edst[h * NNODES + m];
        ev = ev > 0.f ? ev : ALPHA_ * ev;
        pLds[w][j] = ev;
        mLds[w][j] = m;
        mymax = fmaxf(mymax, ev);
    }
    #pragma unroll
    for (int off = 32; off; off >>= 1) mymax = fmaxf(mymax, __shfl_xor(mymax, off));

    float mysum = 0.f;
    for (int j = lane; j < deg; j += 64) {
        const float p = expf(pLds[w][j] - mymax);
        pLds[w][j] = p;
        mysum += p;
    }
    #pragma unroll
    for (int off = 32; off; off >>= 1) mysum += __shfl_xor(mysum, off);

    __syncthreads();

    // Phase 2: lane == output dim d; 128 B coalesced bf16 row reads.
    float acc = 0.f;
    const u16* base = Whb + (long)h * NHID_ + lane;
    #pragma unroll 2
    for (int j = 0; j < deg; ++j)
        acc = fmaf(pLds[w][j], b2f(base[(long)mLds[w][j] * EMB_]), acc);

    float hv = acc / mysum;
    hv = hv > 0.f ? hv : expm1f(hv);                       // ELU
    enc[(long)n * EMB_ + h * NHID_ + lane] = f2b(hv);
}

// ---------------------------------------------------------------------------
extern "C" void kernel_launch(void* const* d_in, const int* in_sizes, int n_in,
                              void* d_out, int out_size, void* d_ws, size_t ws_size,
                              hipStream_t stream)
{
    const float* x   = (const float*)d_in[0];
    const float* adj = (const float*)d_in[1];
    const float* W   = (const float*)d_in[2];
    const float* a1  = (const float*)d_in[3];
    const float* a2  = (const float*)d_in[4];
    const float* W1  = (const float*)d_in[5];
    const float* b1  = (const float*)d_in[6];
    const float* W2  = (const float*)d_in[7];
    const float* b2  = (const float*)d_in[8];
    const float* W3  = (const float*)d_in[9];
    const float* b3  = (const float*)d_in[10];
    const float* W4  = (const float*)d_in[11];
    const float* b4  = (const float*)d_in[12];
    float* out = (float*)d_out;

    // Workspace layout (16B-aligned offsets). dd1..dd3 alias xb (dead after
    // the head GEMM).
    float* Whc = (float*)d_ws;                        // 2,097,152 f (8 MB)
    float* es  = Whc + 2097152;                       //    32,768 f
    float* ed  = es  + 32768;                         //    32,768 f
    u16* Whb = (u16*)(ed + 32768);                    // 2,097,152 us (4 MB)
    u16* enc = Whb + 2097152;                         // 2,097,152 us
    u16* WcT = enc + 2097152;                         //   524,288 us
    u16* W1b = WcT + 524288;                          //   131,072 us
    u16* W2b = W1b + 131072;                          //    65,536 us
    u16* W3b = W2b + 65536;                           //   131,072 us
    u16* W4b = W3b + 131072;                          //   524,288 us
    int* cnt = (int*)(W4b + 524288);                  //     4,096 i
    int* nbr = cnt + 4096;                            // 1,048,576 i
    u16* xb  = (u16*)(nbr + 1048576);                 // 4,194,304 us (8 MB)
    u16* dd1 = xb;                                    // 1,048,576 us (alias)
    u16* dd2 = dd1 + 1048576;                         // 1,048,576 us
    u16* dd3 = dd2 + 1048576;                         // 2,097,152 us

    // 0) fused: neighbor lists + WcT transpose + bf16 casts
    prep_nbr<<<dim3(NNODES + 128 + 256), 256, 0, stream>>>(
        x, adj, W, W1, W2, W3, W4, xb, WcT, W1b, W2b, W3b, W4b, cnt, nbr);

    // 1) head GEMM: Whc/Whb[n, h*64+d] = x @ Wcat (fp32 + bf16 mirror)
    gemm_bt<64, 2, 0><<<dim3(8, 32), 256, 0, stream>>>(
        xb, WcT, nullptr, Whc, Whb, NNODES, EMB_, NFEAT_);

    // 2) attention scores (fp32-exact)
    attn_scores<<<dim3(8192), 256, 0, stream>>>(Whc, a1, a2, es, ed);

    // 3) sparse softmax + aggregate + ELU -> enc (bf16)
    attn_agg<<<dim3(8192), 256, 0, stream>>>(Whb, es, ed, cnt, nbr, enc);

    // 4) decoder MLP (y = x @ W^T + b), bf16 MFMA, fp32 accum
    gemm_bt<32, 1, 1><<<dim3(8, 32), 256, 0, stream>>>(enc, W1b, b1, dd1, nullptr, NNODES, 256, 512);
    gemm_bt<32, 1, 1><<<dim3(8, 32), 256, 0, stream>>>(dd1, W2b, b2, dd2, nullptr, NNODES, 256, 256);
    gemm_bt<64, 1, 1><<<dim3(8, 32), 256, 0, stream>>>(dd2, W3b, b3, dd3, nullptr, NNODES, 512, 256);
    gemm_bt<128, 0, 0><<<dim3(8, 32), 256, 0, stream>>>(dd3, W4b, b4, out, nullptr, NNODES, 1024, 512);
}

// Round 5
// 247.339 us; speedup vs baseline: 1.8379x; 1.0785x over previous
//
#include <hip/hip_runtime.h>
#include <hip/hip_bf16.h>
#include <math.h>

// Problem constants (fixed by the reference)
#define NNODES 4096
#define NFEAT_ 1024
#define NHID_  64
#define NHEADS_ 8
#define EMB_   512
#define MAXD   256
constexpr float ALPHA_ = 0.2f;

typedef __attribute__((ext_vector_type(8))) short bf16x8;  // 8 bf16 (4 VGPRs)
typedef __attribute__((ext_vector_type(4))) float f32x4;   // MFMA accumulator
typedef unsigned int u32;
typedef unsigned short u16;

__device__ inline u16 f2b(float f) {
    __hip_bfloat16 b = __float2bfloat16(f);
    return *(u16*)&b;
}
__device__ inline float b2f(u16 u) {
    return __uint_as_float(((u32)u) << 16);
}

// async global->LDS, 16 B per lane. LDS dest: wave-uniform base + lane*16.
__device__ inline void cp16(const void* g, void* l) {
    __builtin_amdgcn_global_load_lds(
        (const __attribute__((address_space(1))) u32*)g,
        (__attribute__((address_space(3))) u32*)l, 16, 0, 0);
}

// ---------------------------------------------------------------------------
// bf16 MFMA GEMM:  C[M,N] = act( A[M,K] @ B[N,K]^T + bias )
// A, B bf16 row-major (B in B^T form). BM=128, BK=32, 4 waves (2x2).
// Staging via global_load_lds (16 B), linear LDS layout (m97 structure).
// OUTM: 0 = fp32 out, 1 = bf16 out, 2 = fp32 out + bf16 mirror (Cb).
// ACT: 1 = relu.  M%128==0, N%BN==0, K%32==0 at every call site.
// ---------------------------------------------------------------------------
template<int BN, int OUTM, int ACT>
__global__ __launch_bounds__(256) void gemm_bt(
    const u16* __restrict__ A, const u16* __restrict__ B,
    const float* __restrict__ bias, void* __restrict__ Cv,
    u16* __restrict__ Cb, int M, int N, int K)
{
    constexpr int BM = 128, BK = 32;
    constexpr int WN = BN / 2;        // wave column extent
    constexpr int NJ = WN / 16;       // B fragments per wave
    constexpr int BCH = BN / 16;      // B 1KB chunks per K-tile (A has 8)
    __shared__ __align__(16) u16 As[BM * BK];
    __shared__ __align__(16) u16 Bs[BN * BK];

    const int tid  = threadIdx.x;
    const int wid  = tid >> 6, lane = tid & 63;
    const int wr   = wid >> 1, wc = wid & 1;
    const int m0   = blockIdx.y * BM, n0 = blockIdx.x * BN;
    const int frow = lane & 15, fk = (lane >> 4) * 8;
    const int lr   = lane >> 2, lc = (lane & 3) * 8;   // within-chunk row/col

    f32x4 acc[4][NJ] = {};

    for (int k0 = 0; k0 < K; k0 += BK) {
        // A tile [128][32] bf16 = 8 chunks of 1KB; wave w issues chunks w, w+4
        {
            const u16* gA = A + (long)m0 * K + k0;
            int c = wid;
            cp16(gA + (long)(c * 16 + lr) * K + lc, &As[c * 512]);
            c = wid + 4;
            cp16(gA + (long)(c * 16 + lr) * K + lc, &As[c * 512]);
        }
        // B tile [BN][32] = BCH chunks
        {
            const u16* gB = B + (long)n0 * K + k0;
            if (BCH >= 4) {
                int c = wid;
                cp16(gB + (long)(c * 16 + lr) * K + lc, &Bs[c * 512]);
                if (BCH == 8) {
                    c = wid + 4;
                    cp16(gB + (long)(c * 16 + lr) * K + lc, &Bs[c * 512]);
                }
            } else if (wid < BCH) {
                const int c = wid;
                cp16(gB + (long)(c * 16 + lr) * K + lc, &Bs[c * 512]);
            }
        }
        __syncthreads();   // compiler drains vmcnt(0) before s_barrier

        bf16x8 af[4], bfr[NJ];
        #pragma unroll
        for (int i = 0; i < 4; ++i)
            af[i] = *(const bf16x8*)&As[(wr * 64 + i * 16 + frow) * BK + fk];
        #pragma unroll
        for (int j = 0; j < NJ; ++j)
            bfr[j] = *(const bf16x8*)&Bs[(wc * WN + j * 16 + frow) * BK + fk];
        #pragma unroll
        for (int i = 0; i < 4; ++i)
            #pragma unroll
            for (int j = 0; j < NJ; ++j)
                acc[i][j] = __builtin_amdgcn_mfma_f32_16x16x32_bf16(
                    af[i], bfr[j], acc[i][j], 0, 0, 0);
        __syncthreads();
    }

    // epilogue: C/D layout col=lane&15, row=(lane>>4)*4+reg  [m89-verified]
    const int crow0 = m0 + wr * 64 + (lane >> 4) * 4;
    const int ccol0 = n0 + wc * WN + (lane & 15);
    #pragma unroll
    for (int i = 0; i < 4; ++i)
        #pragma unroll
        for (int j = 0; j < NJ; ++j)
            #pragma unroll
            for (int r = 0; r < 4; ++r) {
                const int row = crow0 + i * 16 + r;
                const int col = ccol0 + j * 16;
                float v = acc[i][j][r];
                if (bias) v += bias[col];
                if (ACT == 1) v = v > 0.f ? v : 0.f;
                if (OUTM == 1) ((u16*)Cv)[(long)row * N + col] = f2b(v);
                else           ((float*)Cv)[(long)row * N + col] = v;
                if (OUTM == 2) Cb[(long)row * N + col] = f2b(v);
            }
}

// ---------------------------------------------------------------------------
// Fused prep + neighbor-list build.
//   blocks [0, 4096)      : build_nbr row b from dense adjacency (float4 scan)
//   blocks [4096, 4224)   : WcT LDS tile-transpose (8 heads x 16 k-tiles)
//   blocks [4224, 4480)   : bf16 casts of x and decoder weights (grid-stride)
// ---------------------------------------------------------------------------
__global__ __launch_bounds__(256) void prep_nbr(
    const float* __restrict__ x,   const float* __restrict__ adj,
    const float* __restrict__ W,
    const float* __restrict__ W1,  const float* __restrict__ W2,
    const float* __restrict__ W3,  const float* __restrict__ W4,
    u16* __restrict__ xb,  u16* __restrict__ WcT,
    u16* __restrict__ W1b, u16* __restrict__ W2b,
    u16* __restrict__ W3b, u16* __restrict__ W4b,
    int* __restrict__ cnt, int* __restrict__ nbr)
{
    const int b = blockIdx.x, tid = threadIdx.x;

    if (b < NNODES) {
        // ---- neighbor list for row b ----
        __shared__ int lcnt;
        if (tid == 0) lcnt = 0;
        __syncthreads();
        const float4* arow = (const float4*)(adj + (long)b * NNODES);
        for (int m4 = tid; m4 < NNODES / 4; m4 += 256) {
            const float4 v = arow[m4];
            if (v.x != 0.f) { const int p = atomicAdd(&lcnt, 1); if (p < MAXD) nbr[b * MAXD + p] = m4 * 4; }
            if (v.y != 0.f) { const int p = atomicAdd(&lcnt, 1); if (p < MAXD) nbr[b * MAXD + p] = m4 * 4 + 1; }
            if (v.z != 0.f) { const int p = atomicAdd(&lcnt, 1); if (p < MAXD) nbr[b * MAXD + p] = m4 * 4 + 2; }
            if (v.w != 0.f) { const int p = atomicAdd(&lcnt, 1); if (p < MAXD) nbr[b * MAXD + p] = m4 * 4 + 3; }
        }
        __syncthreads();
        if (tid == 0) cnt[b] = lcnt < MAXD ? lcnt : MAXD;
    } else if (b < NNODES + 128) {
        // ---- WcT[h*64+d][k] = W[h][k][d], 64x64 tile via LDS ----
        __shared__ float tile[64][65];
        const int tb = b - NNODES;
        const int h = tb >> 4, k0 = (tb & 15) * 64;
        #pragma unroll
        for (int p = 0; p < 4; ++p) {
            const int kr = p * 16 + (tid >> 4), d = (tid & 15) * 4;
            const float4 v = *(const float4*)&W[((long)h * NFEAT_ + k0 + kr) * NHID_ + d];
            tile[kr][d] = v.x; tile[kr][d + 1] = v.y;
            tile[kr][d + 2] = v.z; tile[kr][d + 3] = v.w;
        }
        __syncthreads();
        #pragma unroll
        for (int p = 0; p < 4; ++p) {
            const int d = p * 16 + (tid >> 4), k = (tid & 15) * 4;
            ushort4 o;
            o.x = f2b(tile[k][d]);     o.y = f2b(tile[k + 1][d]);
            o.z = f2b(tile[k + 2][d]); o.w = f2b(tile[k + 3][d]);
            *(ushort4*)&WcT[((long)h * 64 + d) * NFEAT_ + k0 + k] = o;
        }
    } else {
        // ---- bf16 casts, grid-stride over 256 blocks ----
        const int np = 256 * 256;
        const int t = (b - NNODES - 128) * 256 + tid;
        for (int i = t; i < (NNODES * NFEAT_) / 4; i += np) {
            const float4 v = ((const float4*)x)[i];
            ushort4 o; o.x = f2b(v.x); o.y = f2b(v.y); o.z = f2b(v.z); o.w = f2b(v.w);
            ((ushort4*)xb)[i] = o;
        }
        for (int i = t; i < (256 * 512) / 4; i += np) {
            const float4 v = ((const float4*)W1)[i];
            ushort4 o; o.x = f2b(v.x); o.y = f2b(v.y); o.z = f2b(v.z); o.w = f2b(v.w);
            ((ushort4*)W1b)[i] = o;
        }
        for (int i = t; i < (256 * 256) / 4; i += np) {
            const float4 v = ((const float4*)W2)[i];
            ushort4 o; o.x = f2b(v.x); o.y = f2b(v.y); o.z = f2b(v.z); o.w = f2b(v.w);
            ((ushort4*)W2b)[i] = o;
        }
        for (int i = t; i < (512 * 256) / 4; i += np) {
            const float4 v = ((const float4*)W3)[i];
            ushort4 o; o.x = f2b(v.x); o.y = f2b(v.y); o.z = f2b(v.z); o.w = f2b(v.w);
            ((ushort4*)W3b)[i] = o;
        }
        for (int i = t; i < (1024 * 512) / 4; i += np) {
            const float4 v = ((const float4*)W4)[i];
            ushort4 o; o.x = f2b(v.x); o.y = f2b(v.y); o.z = f2b(v.z); o.w = f2b(v.w);
            ((ushort4*)W4b)[i] = o;
        }
    }
}

// ---------------------------------------------------------------------------
// e_src[h,n] = Whc[n, h*64+:].a1[h]   e_dst likewise. One wave per (h,n).
// Whc layout: [N, H*nhid] fp32 (exact scores).
// ---------------------------------------------------------------------------
__global__ __launch_bounds__(256) void attn_scores(
    const float* __restrict__ Whc, const float* __restrict__ a1,
    const float* __restrict__ a2, float* __restrict__ esrc,
    float* __restrict__ edst)
{
    const int wave = (blockIdx.x * 256 + threadIdx.x) >> 6;
    const int lane = threadIdx.x & 63;
    const int h = wave >> 12, n = wave & 4095;
    const float w = Whc[(long)n * EMB_ + h * NHID_ + lane];
    float s1 = w * a1[h * NHID_ + lane];
    float s2 = w * a2[h * NHID_ + lane];
    #pragma unroll
    for (int off = 32; off; off >>= 1) {
        s1 += __shfl_xor(s1, off);
        s2 += __shfl_xor(s2, off);
    }
    if (lane == 0) {
        esrc[h * NNODES + n] = s1;
        edst[h * NNODES + n] = s2;
    }
}

// ---------------------------------------------------------------------------
// Sparse masked softmax + aggregation + ELU -> enc (bf16, [N, H*nhid]).
// One wave per (h,n). Softmax fp32-exact; aggregation reads the bf16 mirror.
// Phase 2 runs in 8-wide batches: (p,m) lists padded to a multiple of 8 with
// p=0 / m=0 (exactly-zero contribution), 8 independent gathers in flight.
// ---------------------------------------------------------------------------
__global__ __launch_bounds__(256) void attn_agg(
    const u16* __restrict__ Whb, const float* __restrict__ esrc,
    const float* __restrict__ edst, const int* __restrict__ cnt,
    const int* __restrict__ nbr, u16* __restrict__ enc)
{
    __shared__ __align__(16) float pLds[4][MAXD];
    __shared__ __align__(16) int   mLds[4][MAXD];
    const int w = threadIdx.x >> 6, lane = threadIdx.x & 63;
    const int pair = blockIdx.x * 4 + w;
    const int h = pair >> 12, n = pair & 4095;

    const int deg  = min(cnt[n], MAXD);
    const int degp = (deg + 7) & ~7;            // padded length (<= MAXD)
    const int* lst = nbr + n * MAXD;
    const float es = esrc[h * NNODES + n];

    float mymax = -3.4e38f;
    for (int j = lane; j < deg; j += 64) {
        const int m = lst[j];
        float ev = es + edst[h * NNODES + m];
        ev = ev > 0.f ? ev : ALPHA_ * ev;
        pLds[w][j] = ev;
        mLds[w][j] = m;
        mymax = fmaxf(mymax, ev);
    }
    // pad tail with exact zeros (p=0 contributes nothing; m=0 is in-bounds)
    for (int j = deg + lane; j < degp; j += 64) {
        pLds[w][j] = 0.f;
        mLds[w][j] = 0;
    }
    #pragma unroll
    for (int off = 32; off; off >>= 1) mymax = fmaxf(mymax, __shfl_xor(mymax, off));

    float mysum = 0.f;
    for (int j = lane; j < deg; j += 64) {
        const float p = __expf(pLds[w][j] - mymax);
        pLds[w][j] = p;
        mysum += p;
    }
    #pragma unroll
    for (int off = 32; off; off >>= 1) mysum += __shfl_xor(mysum, off);

    __syncthreads();

    // Phase 2: lane == output dim d. 8 gathers in flight per wave.
    float acc = 0.f;
    const u16* base = Whb + (long)h * NHID_ + lane;
    for (int j0 = 0; j0 < degp; j0 += 8) {
        const int4   ma = *(const int4*)&mLds[w][j0];
        const int4   mb = *(const int4*)&mLds[w][j0 + 4];
        const float4 pa = *(const float4*)&pLds[w][j0];
        const float4 pb = *(const float4*)&pLds[w][j0 + 4];
        const float v0 = b2f(base[(long)ma.x << 9]);
        const float v1 = b2f(base[(long)ma.y << 9]);
        const float v2 = b2f(base[(long)ma.z << 9]);
        const float v3 = b2f(base[(long)ma.w << 9]);
        const float v4 = b2f(base[(long)mb.x << 9]);
        const float v5 = b2f(base[(long)mb.y << 9]);
        const float v6 = b2f(base[(long)mb.z << 9]);
        const float v7 = b2f(base[(long)mb.w << 9]);
        acc = fmaf(pa.x, v0, acc);
        acc = fmaf(pa.y, v1, acc);
        acc = fmaf(pa.z, v2, acc);
        acc = fmaf(pa.w, v3, acc);
        acc = fmaf(pb.x, v4, acc);
        acc = fmaf(pb.y, v5, acc);
        acc = fmaf(pb.z, v6, acc);
        acc = fmaf(pb.w, v7, acc);
    }

    float hv = acc / mysum;
    hv = hv > 0.f ? hv : expm1f(hv);                       // ELU
    enc[(long)n * EMB_ + h * NHID_ + lane] = f2b(hv);
}

// ---------------------------------------------------------------------------
extern "C" void kernel_launch(void* const* d_in, const int* in_sizes, int n_in,
                              void* d_out, int out_size, void* d_ws, size_t ws_size,
                              hipStream_t stream)
{
    const float* x   = (const float*)d_in[0];
    const float* adj = (const float*)d_in[1];
    const float* W   = (const float*)d_in[2];
    const float* a1  = (const float*)d_in[3];
    const float* a2  = (const float*)d_in[4];
    const float* W1  = (const float*)d_in[5];
    const float* b1  = (const float*)d_in[6];
    const float* W2  = (const float*)d_in[7];
    const float* b2  = (const float*)d_in[8];
    const float* W3  = (const float*)d_in[9];
    const float* b3  = (const float*)d_in[10];
    const float* W4  = (const float*)d_in[11];
    const float* b4  = (const float*)d_in[12];
    float* out = (float*)d_out;

    // Workspace layout (16B-aligned offsets). dd1..dd3 alias xb (dead after
    // the head GEMM).
    float* Whc = (float*)d_ws;                        // 2,097,152 f (8 MB)
    float* es  = Whc + 2097152;                       //    32,768 f
    float* ed  = es  + 32768;                         //    32,768 f
    u16* Whb = (u16*)(ed + 32768);                    // 2,097,152 us (4 MB)
    u16* enc = Whb + 2097152;                         // 2,097,152 us
    u16* WcT = enc + 2097152;                         //   524,288 us
    u16* W1b = WcT + 524288;                          //   131,072 us
    u16* W2b = W1b + 131072;                          //    65,536 us
    u16* W3b = W2b + 65536;                           //   131,072 us
    u16* W4b = W3b + 131072;                          //   524,288 us
    int* cnt = (int*)(W4b + 524288);                  //     4,096 i
    int* nbr = cnt + 4096;                            // 1,048,576 i
    u16* xb  = (u16*)(nbr + 1048576);                 // 4,194,304 us (8 MB)
    u16* dd1 = xb;                                    // 1,048,576 us (alias)
    u16* dd2 = dd1 + 1048576;                         // 1,048,576 us
    u16* dd3 = dd2 + 1048576;                         // 2,097,152 us

    // 0) fused: neighbor lists + WcT transpose + bf16 casts
    prep_nbr<<<dim3(NNODES + 128 + 256), 256, 0, stream>>>(
        x, adj, W, W1, W2, W3, W4, xb, WcT, W1b, W2b, W3b, W4b, cnt, nbr);

    // 1) head GEMM: Whc/Whb[n, h*64+d] = x @ Wcat (fp32 + bf16 mirror)
    gemm_bt<64, 2, 0><<<dim3(8, 32), 256, 0, stream>>>(
        xb, WcT, nullptr, Whc, Whb, NNODES, EMB_, NFEAT_);

    // 2) attention scores (fp32-exact)
    attn_scores<<<dim3(8192), 256, 0, stream>>>(Whc, a1, a2, es, ed);

    // 3) sparse softmax + aggregate + ELU -> enc (bf16)
    attn_agg<<<dim3(8192), 256, 0, stream>>>(Whb, es, ed, cnt, nbr, enc);

    // 4) decoder MLP (y = x @ W^T + b), bf16 MFMA, fp32 accum
    gemm_bt<32, 1, 1><<<dim3(8, 32), 256, 0, stream>>>(enc, W1b, b1, dd1, nullptr, NNODES, 256, 512);
    gemm_bt<32, 1, 1><<<dim3(8, 32), 256, 0, stream>>>(dd1, W2b, b2, dd2, nullptr, NNODES, 256, 256);
    gemm_bt<64, 1, 1><<<dim3(8, 32), 256, 0, stream>>>(dd2, W3b, b3, dd3, nullptr, NNODES, 512, 256);
    gemm_bt<128, 0, 0><<<dim3(8, 32), 256, 0, stream>>>(dd3, W4b, b4, out, nullptr, NNODES, 1024, 512);
}

// Round 6
// 229.673 us; speedup vs baseline: 1.9793x; 1.0769x over previous
//
#include <hip/hip_runtime.h>
#include <hip/hip_bf16.h>
#include <math.h>

// Problem constants (fixed by the reference)
#define NNODES 4096
#define NFEAT_ 1024
#define NHID_  64
#define NHEADS_ 8
#define EMB_   512
#define MAXD   256
constexpr float ALPHA_ = 0.2f;

typedef __attribute__((ext_vector_type(8))) short bf16x8;  // 8 bf16 (4 VGPRs)
typedef __attribute__((ext_vector_type(4))) float f32x4;   // MFMA accumulator
typedef unsigned int u32;
typedef unsigned short u16;

__device__ inline u16 f2b(float f) {
    __hip_bfloat16 b = __float2bfloat16(f);
    return *(u16*)&b;
}
__device__ inline float b2f(u16 u) {
    return __uint_as_float(((u32)u) << 16);
}

// async global->LDS, 16 B per lane. LDS dest: wave-uniform base + lane*16.
__device__ inline void cp16(const void* g, void* l) {
    __builtin_amdgcn_global_load_lds(
        (const __attribute__((address_space(1))) u32*)g,
        (__attribute__((address_space(3))) u32*)l, 16, 0, 0);
}

// ---------------------------------------------------------------------------
// bf16 MFMA GEMM:  C[M,N] = act( A[M,K] @ B[N,K]^T + bias )
// A, B bf16 row-major (B in B^T form). 4 waves (2x2), double-buffered LDS:
// stage(next) issued before compute(cur), one __syncthreads per K-step, so
// global_load_lds latency overlaps the MFMA phase (we run 1-2 blocks/CU).
// OUTM: 0 = fp32 out, 1 = bf16 out.   ACT: 1 = relu.
// SCORES (requires BN==64): block owns (head h = n0/64, rows m0..m0+BM);
// epilogue computes es/ed row-dots from the fp32 accumulators.
// M%BM==0, N%BN==0, K%32==0 at every call site.
// ---------------------------------------------------------------------------
template<int BM, int BN, int OUTM, int ACT, bool SCORES>
__global__ __launch_bounds__(256) void gemm_bt(
    const u16* __restrict__ A, const u16* __restrict__ B,
    const float* __restrict__ bias, void* __restrict__ Cv,
    const float* __restrict__ a1, const float* __restrict__ a2,
    float* __restrict__ es, float* __restrict__ ed,
    int M, int N, int K)
{
    constexpr int BK  = 32;
    constexpr int WM  = BM / 2;       // wave row extent
    constexpr int MI  = WM / 16;      // A fragments per wave
    constexpr int WN  = BN / 2;       // wave column extent
    constexpr int NJ  = WN / 16;      // B fragments per wave
    constexpr int ACH = BM / 16;      // A 1KB chunks per K-tile (4 or 8)
    constexpr int BCH = BN / 16;      // B 1KB chunks per K-tile (2,4,8)
    static_assert(!SCORES || BN == 64, "SCORES assumes one head per block");

    __shared__ __align__(16) u16 As[2][BM * BK];
    __shared__ __align__(16) u16 Bs[2][BN * BK];
    __shared__ float s1Lds[SCORES ? 2 : 1][SCORES ? BM : 1];
    __shared__ float s2Lds[SCORES ? 2 : 1][SCORES ? BM : 1];

    const int tid  = threadIdx.x;
    const int wid  = tid >> 6, lane = tid & 63;
    const int wr   = wid >> 1, wc = wid & 1;
    const int m0   = blockIdx.y * BM, n0 = blockIdx.x * BN;
    const int frow = lane & 15, fk = (lane >> 4) * 8;
    const int lr   = lane >> 2, lc = (lane & 3) * 8;   // within-chunk row/col

    auto stage = [&](int buf, int k0) {
        const u16* gA = A + (long)m0 * K + k0;
        {
            int c = wid;
            cp16(gA + (long)(c * 16 + lr) * K + lc, &As[buf][c * 512]);
            if (ACH == 8) {
                c = wid + 4;
                cp16(gA + (long)(c * 16 + lr) * K + lc, &As[buf][c * 512]);
            }
        }
        const u16* gB = B + (long)n0 * K + k0;
        if (BCH >= 4) {
            int c = wid;
            cp16(gB + (long)(c * 16 + lr) * K + lc, &Bs[buf][c * 512]);
            if (BCH == 8) {
                c = wid + 4;
                cp16(gB + (long)(c * 16 + lr) * K + lc, &Bs[buf][c * 512]);
            }
        } else if (wid < BCH) {
            cp16(gB + (long)(wid * 16 + lr) * K + lc, &Bs[buf][wid * 512]);
        }
    };

    f32x4 acc[MI][NJ] = {};

    stage(0, 0);
    __syncthreads();                  // drains vmcnt(0) before barrier
    int cur = 0;
    for (int k0 = 0; k0 < K; k0 += BK) {
        if (k0 + BK < K) stage(cur ^ 1, k0 + BK);   // overlap with compute

        bf16x8 af[MI], bfr[NJ];
        #pragma unroll
        for (int i = 0; i < MI; ++i)
            af[i] = *(const bf16x8*)&As[cur][(wr * WM + i * 16 + frow) * BK + fk];
        #pragma unroll
        for (int j = 0; j < NJ; ++j)
            bfr[j] = *(const bf16x8*)&Bs[cur][(wc * WN + j * 16 + frow) * BK + fk];
        #pragma unroll
        for (int i = 0; i < MI; ++i)
            #pragma unroll
            for (int j = 0; j < NJ; ++j)
                acc[i][j] = __builtin_amdgcn_mfma_f32_16x16x32_bf16(
                    af[i], bfr[j], acc[i][j], 0, 0, 0);

        __syncthreads();              // next tile staged + cur reads done
        cur ^= 1;
    }

    // epilogue: C/D layout col=lane&15, row=(lane>>4)*4+reg  [m89-verified]
    const int crow0 = m0 + wr * WM + (lane >> 4) * 4;
    const int ccol0 = n0 + wc * WN + (lane & 15);
    #pragma unroll
    for (int i = 0; i < MI; ++i)
        #pragma unroll
        for (int j = 0; j < NJ; ++j)
            #pragma unroll
            for (int r = 0; r < 4; ++r) {
                const int row = crow0 + i * 16 + r;
                const int col = ccol0 + j * 16;
                float v = acc[i][j][r];
                if (bias) v += bias[col];
                if (ACT == 1) v = v > 0.f ? v : 0.f;
                if (OUTM == 1) ((u16*)Cv)[(long)row * N + col] = f2b(v);
                else           ((float*)Cv)[(long)row * N + col] = v;
            }

    if constexpr (SCORES) {
        // e_src/e_dst for this block's (head, BM rows) from fp32 accumulators
        const int h = n0 >> 6;
        const float a1v0 = a1[h * 64 + wc * WN + frow];
        const float a1v1 = a1[h * 64 + wc * WN + 16 + frow];
        const float a2v0 = a2[h * 64 + wc * WN + frow];
        const float a2v1 = a2[h * 64 + wc * WN + 16 + frow];
        #pragma unroll
        for (int i = 0; i < MI; ++i)
            #pragma unroll
            for (int r = 0; r < 4; ++r) {
                float s1 = acc[i][0][r] * a1v0 + acc[i][1][r] * a1v1;
                float s2 = acc[i][0][r] * a2v0 + acc[i][1][r] * a2v1;
                #pragma unroll
                for (int off = 8; off; off >>= 1) {
                    s1 += __shfl_xor(s1, off);
                    s2 += __shfl_xor(s2, off);
                }
                if (frow == 0) {
                    const int row = wr * WM + i * 16 + (lane >> 4) * 4 + r;
                    s1Lds[wc][row] = s1;
                    s2Lds[wc][row] = s2;
                }
            }
        __syncthreads();
        if (tid < BM) {
            es[h * NNODES + m0 + tid] = s1Lds[0][tid] + s1Lds[1][tid];
            ed[h * NNODES + m0 + tid] = s2Lds[0][tid] + s2Lds[1][tid];
        }
    }
}

// ---------------------------------------------------------------------------
// Fused prep + neighbor-list build.
//   blocks [0, 4096)      : build_nbr row b from dense adjacency (float4 scan)
//   blocks [4096, 4224)   : WcT LDS tile-transpose (8 heads x 16 k-tiles)
//   blocks [4224, 4480)   : bf16 casts of x and decoder weights (grid-stride)
// ---------------------------------------------------------------------------
__global__ __launch_bounds__(256) void prep_nbr(
    const float* __restrict__ x,   const float* __restrict__ adj,
    const float* __restrict__ W,
    const float* __restrict__ W1,  const float* __restrict__ W2,
    const float* __restrict__ W3,  const float* __restrict__ W4,
    u16* __restrict__ xb,  u16* __restrict__ WcT,
    u16* __restrict__ W1b, u16* __restrict__ W2b,
    u16* __restrict__ W3b, u16* __restrict__ W4b,
    int* __restrict__ cnt, int* __restrict__ nbr)
{
    const int b = blockIdx.x, tid = threadIdx.x;

    if (b < NNODES) {
        // ---- neighbor list for row b ----
        __shared__ int lcnt;
        if (tid == 0) lcnt = 0;
        __syncthreads();
        const float4* arow = (const float4*)(adj + (long)b * NNODES);
        for (int m4 = tid; m4 < NNODES / 4; m4 += 256) {
            const float4 v = arow[m4];
            if (v.x != 0.f) { const int p = atomicAdd(&lcnt, 1); if (p < MAXD) nbr[b * MAXD + p] = m4 * 4; }
            if (v.y != 0.f) { const int p = atomicAdd(&lcnt, 1); if (p < MAXD) nbr[b * MAXD + p] = m4 * 4 + 1; }
            if (v.z != 0.f) { const int p = atomicAdd(&lcnt, 1); if (p < MAXD) nbr[b * MAXD + p] = m4 * 4 + 2; }
            if (v.w != 0.f) { const int p = atomicAdd(&lcnt, 1); if (p < MAXD) nbr[b * MAXD + p] = m4 * 4 + 3; }
        }
        __syncthreads();
        if (tid == 0) cnt[b] = lcnt < MAXD ? lcnt : MAXD;
    } else if (b < NNODES + 128) {
        // ---- WcT[h*64+d][k] = W[h][k][d], 64x64 tile via LDS ----
        __shared__ float tile[64][65];
        const int tb = b - NNODES;
        const int h = tb >> 4, k0 = (tb & 15) * 64;
        #pragma unroll
        for (int p = 0; p < 4; ++p) {
            const int kr = p * 16 + (tid >> 4), d = (tid & 15) * 4;
            const float4 v = *(const float4*)&W[((long)h * NFEAT_ + k0 + kr) * NHID_ + d];
            tile[kr][d] = v.x; tile[kr][d + 1] = v.y;
            tile[kr][d + 2] = v.z; tile[kr][d + 3] = v.w;
        }
        __syncthreads();
        #pragma unroll
        for (int p = 0; p < 4; ++p) {
            const int d = p * 16 + (tid >> 4), k = (tid & 15) * 4;
            ushort4 o;
            o.x = f2b(tile[k][d]);     o.y = f2b(tile[k + 1][d]);
            o.z = f2b(tile[k + 2][d]); o.w = f2b(tile[k + 3][d]);
            *(ushort4*)&WcT[((long)h * 64 + d) * NFEAT_ + k0 + k] = o;
        }
    } else {
        // ---- bf16 casts, grid-stride over 256 blocks ----
        const int np = 256 * 256;
        const int t = (b - NNODES - 128) * 256 + tid;
        for (int i = t; i < (NNODES * NFEAT_) / 4; i += np) {
            const float4 v = ((const float4*)x)[i];
            ushort4 o; o.x = f2b(v.x); o.y = f2b(v.y); o.z = f2b(v.z); o.w = f2b(v.w);
            ((ushort4*)xb)[i] = o;
        }
        for (int i = t; i < (256 * 512) / 4; i += np) {
            const float4 v = ((const float4*)W1)[i];
            ushort4 o; o.x = f2b(v.x); o.y = f2b(v.y); o.z = f2b(v.z); o.w = f2b(v.w);
            ((ushort4*)W1b)[i] = o;
        }
        for (int i = t; i < (256 * 256) / 4; i += np) {
            const float4 v = ((const float4*)W2)[i];
            ushort4 o; o.x = f2b(v.x); o.y = f2b(v.y); o.z = f2b(v.z); o.w = f2b(v.w);
            ((ushort4*)W2b)[i] = o;
        }
        for (int i = t; i < (512 * 256) / 4; i += np) {
            const float4 v = ((const float4*)W3)[i];
            ushort4 o; o.x = f2b(v.x); o.y = f2b(v.y); o.z = f2b(v.z); o.w = f2b(v.w);
            ((ushort4*)W3b)[i] = o;
        }
        for (int i = t; i < (1024 * 512) / 4; i += np) {
            const float4 v = ((const float4*)W4)[i];
            ushort4 o; o.x = f2b(v.x); o.y = f2b(v.y); o.z = f2b(v.z); o.w = f2b(v.w);
            ((ushort4*)W4b)[i] = o;
        }
    }
}

// ---------------------------------------------------------------------------
// Sparse masked softmax + aggregation + ELU -> enc (bf16, [N, H*nhid]).
// One wave per (h,n). Softmax fp32-exact; aggregation reads the bf16 Whb.
// Phase 2 runs 16-wide: (p,m) lists padded with p=0/m=0 (exact zero
// contribution), 16 independent gathers in flight per wave.
// ---------------------------------------------------------------------------
__global__ __launch_bounds__(256) void attn_agg(
    const u16* __restrict__ Whb, const float* __restrict__ esrc,
    const float* __restrict__ edst, const int* __restrict__ cnt,
    const int* __restrict__ nbr, u16* __restrict__ enc)
{
    __shared__ __align__(16) float pLds[4][MAXD];
    __shared__ __align__(16) int   mLds[4][MAXD];
    const int w = threadIdx.x >> 6, lane = threadIdx.x & 63;
    const int pair = blockIdx.x * 4 + w;
    const int h = pair >> 12, n = pair & 4095;

    const int deg  = min(cnt[n], MAXD);
    const int degp = (deg + 15) & ~15;           // padded length (<= MAXD)
    const int* lst = nbr + n * MAXD;
    const float es = esrc[h * NNODES + n];

    float mymax = -3.4e38f;
    for (int j = lane; j < deg; j += 64) {
        const int m = lst[j];
        float ev = es + edst[h * NNODES + m];
        ev = ev > 0.f ? ev : ALPHA_ * ev;
        pLds[w][j] = ev;
        mLds[w][j] = m;
        mymax = fmaxf(mymax, ev);
    }
    // pad tail with exact zeros (p=0 contributes nothing; m=0 is in-bounds)
    for (int j = deg + lane; j < degp; j += 64) {
        pLds[w][j] = 0.f;
        mLds[w][j] = 0;
    }
    #pragma unroll
    for (int off = 32; off; off >>= 1) mymax = fmaxf(mymax, __shfl_xor(mymax, off));

    float mysum = 0.f;
    for (int j = lane; j < deg; j += 64) {
        const float p = __expf(pLds[w][j] - mymax);
        pLds[w][j] = p;
        mysum += p;
    }
    #pragma unroll
    for (int off = 32; off; off >>= 1) mysum += __shfl_xor(mysum, off);

    __syncthreads();

    // Phase 2: lane == output dim d. 16 gathers in flight per wave.
    float acc = 0.f;
    const u16* base = Whb + (long)h * NHID_ + lane;
    for (int j0 = 0; j0 < degp; j0 += 16) {
        const int4   ma = *(const int4*)&mLds[w][j0];
        const int4   mb = *(const int4*)&mLds[w][j0 + 4];
        const int4   mc = *(const int4*)&mLds[w][j0 + 8];
        const int4   md = *(const int4*)&mLds[w][j0 + 12];
        const float4 pa = *(const float4*)&pLds[w][j0];
        const float4 pb = *(const float4*)&pLds[w][j0 + 4];
        const float4 pc = *(const float4*)&pLds[w][j0 + 8];
        const float4 pd = *(const float4*)&pLds[w][j0 + 12];
        const float v0  = b2f(base[(long)ma.x << 9]);
        const float v1  = b2f(base[(long)ma.y << 9]);
        const float v2  = b2f(base[(long)ma.z << 9]);
        const float v3  = b2f(base[(long)ma.w << 9]);
        const float v4  = b2f(base[(long)mb.x << 9]);
        const float v5  = b2f(base[(long)mb.y << 9]);
        const float v6  = b2f(base[(long)mb.z << 9]);
        const float v7  = b2f(base[(long)mb.w << 9]);
        const float v8  = b2f(base[(long)mc.x << 9]);
        const float v9  = b2f(base[(long)mc.y << 9]);
        const float v10 = b2f(base[(long)mc.z << 9]);
        const float v11 = b2f(base[(long)mc.w << 9]);
        const float v12 = b2f(base[(long)md.x << 9]);
        const float v13 = b2f(base[(long)md.y << 9]);
        const float v14 = b2f(base[(long)md.z << 9]);
        const float v15 = b2f(base[(long)md.w << 9]);
        acc = fmaf(pa.x, v0,  acc); acc = fmaf(pa.y, v1,  acc);
        acc = fmaf(pa.z, v2,  acc); acc = fmaf(pa.w, v3,  acc);
        acc = fmaf(pb.x, v4,  acc); acc = fmaf(pb.y, v5,  acc);
        acc = fmaf(pb.z, v6,  acc); acc = fmaf(pb.w, v7,  acc);
        acc = fmaf(pc.x, v8,  acc); acc = fmaf(pc.y, v9,  acc);
        acc = fmaf(pc.z, v10, acc); acc = fmaf(pc.w, v11, acc);
        acc = fmaf(pd.x, v12, acc); acc = fmaf(pd.y, v13, acc);
        acc = fmaf(pd.z, v14, acc); acc = fmaf(pd.w, v15, acc);
    }

    float hv = acc / mysum;
    hv = hv > 0.f ? hv : expm1f(hv);                       // ELU
    enc[(long)n * EMB_ + h * NHID_ + lane] = f2b(hv);
}

// ---------------------------------------------------------------------------
extern "C" void kernel_launch(void* const* d_in, const int* in_sizes, int n_in,
                              void* d_out, int out_size, void* d_ws, size_t ws_size,
                              hipStream_t stream)
{
    const float* x   = (const float*)d_in[0];
    const float* adj = (const float*)d_in[1];
    const float* W   = (const float*)d_in[2];
    const float* a1  = (const float*)d_in[3];
    const float* a2  = (const float*)d_in[4];
    const float* W1  = (const float*)d_in[5];
    const float* b1  = (const float*)d_in[6];
    const float* W2  = (const float*)d_in[7];
    const float* b2  = (const float*)d_in[8];
    const float* W3  = (const float*)d_in[9];
    const float* b3  = (const float*)d_in[10];
    const float* W4  = (const float*)d_in[11];
    const float* b4  = (const float*)d_in[12];
    float* out = (float*)d_out;

    // Workspace layout (16B-aligned offsets). dd1..dd3 alias xb (dead after
    // the head GEMM).
    float* es  = (float*)d_ws;                        //    32,768 f
    float* ed  = es + 32768;                          //    32,768 f
    u16* Whb = (u16*)(ed + 32768);                    // 2,097,152 us (4 MB)
    u16* enc = Whb + 2097152;                         // 2,097,152 us
    u16* WcT = enc + 2097152;                         //   524,288 us
    u16* W1b = WcT + 524288;                          //   131,072 us
    u16* W2b = W1b + 131072;                          //    65,536 us
    u16* W3b = W2b + 65536;                           //   131,072 us
    u16* W4b = W3b + 131072;                          //   524,288 us
    int* cnt = (int*)(W4b + 524288);                  //     4,096 i
    int* nbr = cnt + 4096;                            // 1,048,576 i
    u16* xb  = (u16*)(nbr + 1048576);                 // 4,194,304 us (8 MB)
    u16* dd1 = xb;                                    // 1,048,576 us (alias)
    u16* dd2 = dd1 + 1048576;                         // 1,048,576 us
    u16* dd3 = dd2 + 1048576;                         // 2,097,152 us

    // 0) fused: neighbor lists + WcT transpose + bf16 casts
    prep_nbr<<<dim3(NNODES + 128 + 256), 256, 0, stream>>>(
        x, adj, W, W1, W2, W3, W4, xb, WcT, W1b, W2b, W3b, W4b, cnt, nbr);

    // 1) head GEMM -> Whb bf16 [n, h*64+d] + fused e_src/e_dst (fp32-exact)
    gemm_bt<64, 64, 1, 0, true><<<dim3(8, 64), 256, 0, stream>>>(
        xb, WcT, nullptr, Whb, a1, a2, es, ed, NNODES, EMB_, NFEAT_);

    // 2) sparse softmax + aggregate + ELU -> enc (bf16)
    attn_agg<<<dim3(8192), 256, 0, stream>>>(Whb, es, ed, cnt, nbr, enc);

    // 3) decoder MLP (y = x @ W^T + b), bf16 MFMA, fp32 accum
    gemm_bt<64, 32, 1, 1, false><<<dim3(8, 64), 256, 0, stream>>>(
        enc, W1b, b1, dd1, nullptr, nullptr, nullptr, nullptr, NNODES, 256, 512);
    gemm_bt<64, 32, 1, 1, false><<<dim3(8, 64), 256, 0, stream>>>(
        dd1, W2b, b2, dd2, nullptr, nullptr, nullptr, nullptr, NNODES, 256, 256);
    gemm_bt<64, 64, 1, 1, false><<<dim3(8, 64), 256, 0, stream>>>(
        dd2, W3b, b3, dd3, nullptr, nullptr, nullptr, nullptr, NNODES, 512, 256);
    gemm_bt<128, 128, 0, 0, false><<<dim3(8, 32), 256, 0, stream>>>(
        dd3, W4b, b4, out, nullptr, nullptr, nullptr, nullptr, NNODES, 1024, 512);
}